// Round 9
// baseline (51.076 us; speedup 1.0000x reference)
//
#include <hip/hip_runtime.h>
#include <stdint.h>

// FlagBagEncoder: out[t,:] = mean over {k : flags[t,k] > 0.5} of W[k,:], zeros if empty.
// T=100000, K=512, D=64, fp32 in/out.
//
// v9: BARRIER-FREE main kernel. v8's __syncthreads (after staging, before phase M)
// synced each block on its slowest wave's stream and serialized the store tail.
// Now: prep kernel packs W -> g_bfrag (64 KB global, L2-hot for all blocks); the
// main kernel has no block-wide sync at all. Per wave: phase L (32-KB contiguous
// flag stream from cycle 0, depth-4 ring) -> private 1-KB LDS mask exchange
// (wave-internal lgkmcnt only) -> phase M (B from L2, depth-2 ring; af + exact
// popc counts from sM bytes) -> scaled stores. Waves fully decoupled.
// Register diet to hold <=64 VGPR (32 waves/CU): no mbytes[16] array (per-step
// ds_read_u8), cnt accumulated in the MFMA loop.
// k-map (identical for A and B, permutation cancels): k = 128*kq + 8*s + e.

#define T_ROWS 100000
#define K_FLAGS 512
#define D_DIM 64
#define TILES (T_ROWS / 16)   // 6250, exact

typedef __attribute__((ext_vector_type(4))) float f32x4;
typedef __attribute__((ext_vector_type(8))) short bf16x8;

// 16 k-steps x 4 n-tiles x 64 lanes x 4 dwords = 64 KB of prepacked B fragments.
__device__ uint32_t g_bfrag[16 * 4 * 64 * 4];

__device__ __forceinline__ uint32_t f32_to_bf16_rne(float f) {
  union { float f; uint32_t u; } v; v.f = f;
  uint32_t u = v.u;
  return (u + 0x7FFFu + ((u >> 16) & 1u)) >> 16;
}

// layout: g_bfrag[E], E = s*256 + nt*64 + lane (uint4 each)
// lane l: col n = (l&15)+16*nt ; k = 128*(l>>4) + 8*s + e ; dword j = elems (2j,2j+1) lo|hi
__global__ void prep_b_kernel(const float* __restrict__ W) {
  int E = blockIdx.x * blockDim.x + threadIdx.x;
  if (E >= 16 * 4 * 64) return;
  int lane = E & 63;
  int nt   = (E >> 6) & 3;
  int s    = E >> 8;
  int n    = (lane & 15) + 16 * nt;
  int kb   = 128 * (lane >> 4) + 8 * s;
  uint32_t r[4];
#pragma unroll
  for (int j = 0; j < 4; ++j) {
    uint32_t lo = f32_to_bf16_rne(W[(size_t)(kb + 2 * j    ) * D_DIM + n]);
    uint32_t hi = f32_to_bf16_rne(W[(size_t)(kb + 2 * j + 1) * D_DIM + n]);
    r[j] = lo | (hi << 16);
  }
  *reinterpret_cast<uint4*>(&g_bfrag[(size_t)E * 4]) = make_uint4(r[0], r[1], r[2], r[3]);
}

__global__ __launch_bounds__(1024, 8) void flagbag_kernel(const float* __restrict__ flags,
                                                          float* __restrict__ out) {
  __shared__ uint32_t sM[16][256];      // 1 KB per wave mask exchange (private per wave)

  const int tid  = threadIdx.x;
  const int lane = tid & 63;
  const int wave = tid >> 6;
  const int tile = wave * 512 + (int)blockIdx.x;   // grid = 512 blocks exactly
  if (tile >= TILES) return;           // no barrier anywhere -> immediate exit is safe

  const int t0 = tile * 16;

  // ---- phase L: row-sequential contiguous read of the 32-KB tile (from cycle 0) ----
  const float* ft = flags + (size_t)t0 * K_FLAGS + lane * 8;

  uint32_t D0 = 0, D1 = 0, D2 = 0, D3 = 0;   // rows 0-3 / 4-7 / 8-11 / 12-15
  f32x4 ra[4], rb[4];
#pragma unroll
  for (int r = 0; r < 3; ++r) {
    ra[r] = *reinterpret_cast<const f32x4*>(ft + r * K_FLAGS);
    rb[r] = *reinterpret_cast<const f32x4*>(ft + r * K_FLAGS + 4);
  }
#pragma unroll
  for (int r = 0; r < 16; ++r) {
    if (r + 3 < 16) {   // compile-time under full unroll
      ra[(r + 3) & 3] = *reinterpret_cast<const f32x4*>(ft + (r + 3) * K_FLAGS);
      rb[(r + 3) & 3] = *reinterpret_cast<const f32x4*>(ft + (r + 3) * K_FLAGS + 4);
    }
    const f32x4 a = ra[r & 3], b = rb[r & 3];
    uint32_t byte = 0;
#pragma unroll
    for (int j = 0; j < 4; ++j) {
      byte |= (a[j] > 0.5f) ? (1u << j)       : 0u;
      byte |= (b[j] > 0.5f) ? (1u << (j + 4)) : 0u;
    }
    const uint32_t sh = byte << ((r & 3) * 8);
    if ((r >> 2) == 0) D0 |= sh;
    else if ((r >> 2) == 1) D1 |= sh;
    else if ((r >> 2) == 2) D2 |= sh;
    else D3 |= sh;
  }

  uint32_t* sMw = sM[wave];
  sMw[0 * 64 + (lane ^ 0)]  = D0;
  sMw[1 * 64 + (lane ^ 4)]  = D1;
  sMw[2 * 64 + (lane ^ 8)]  = D2;
  sMw[3 * 64 + (lane ^ 12)] = D3;
  // wave-internal LDS write->read: compiler inserts the lgkmcnt wait; no block sync needed.

  // ---- phase M: MFMA; B from L2-hot g_bfrag (depth-2 ring), mask bytes from sM ----
  const int m  = lane & 15;   // A row within tile / output col within n-tile
  const int kq = lane >> 4;
  const int mj = m >> 2, mb = m & 3;
  const int m4 = 4 * mj;
  // byte address of step-s mask byte: 4*(mj*64 + (16*kq | (s^m4))) + mb = C + 4*(s^m4)
  const uint8_t* sMb = reinterpret_cast<const uint8_t*>(sMw);
  const int C = 4 * (mj * 64 + 16 * kq) + mb;

  const uint4* gb = reinterpret_cast<const uint4*>(g_bfrag) + lane;

  f32x4 acc[4];
#pragma unroll
  for (int nt = 0; nt < 4; ++nt) acc[nt] = (f32x4){0.f, 0.f, 0.f, 0.f};

  uint4 bc[4], bn[4];
#pragma unroll
  for (int nt = 0; nt < 4; ++nt) bc[nt] = gb[nt * 64];

  int cnt = 0;
#pragma unroll
  for (int s = 0; s < 16; ++s) {
    if (s + 1 < 16) {
#pragma unroll
      for (int nt = 0; nt < 4; ++nt) bn[nt] = gb[((s + 1) * 4 + nt) * 64];
    }
    const uint32_t byte = sMb[C + 4 * (s ^ m4)];   // 8 k-bits of row m, k=128kq+8s+e
    cnt += __popc(byte);
    bf16x8 af;
#pragma unroll
    for (int e = 0; e < 8; ++e) af[e] = ((byte >> e) & 1u) ? (short)0x3F80 : (short)0;

#pragma unroll
    for (int nt = 0; nt < 4; ++nt)
      acc[nt] = __builtin_amdgcn_mfma_f32_16x16x32_bf16(
          af, *reinterpret_cast<const bf16x8*>(&bc[nt]), acc[nt], 0, 0, 0);

#pragma unroll
    for (int nt = 0; nt < 4; ++nt) bc[nt] = bn[nt];
  }

  // full row-m count: lanes {m, m+16, m+32, m+48} hold disjoint k-quarters
  cnt += __shfl_xor(cnt, 16);
  cnt += __shfl_xor(cnt, 32);
  const float inv = (cnt > 0) ? (1.0f / (float)cnt) : 0.0f;

  // ---- epilogue: C/D layout col = lane&15, row = kq*4 + reg ----
#pragma unroll
  for (int r = 0; r < 4; ++r) {
    const int row = kq * 4 + r;
    const float invr = __shfl(inv, row);   // lane 'row' holds that row's count
    float* orow = out + (size_t)(t0 + row) * D_DIM + m;
#pragma unroll
    for (int nt = 0; nt < 4; ++nt)
      orow[16 * nt] = acc[nt][r] * invr;
  }
}

extern "C" void kernel_launch(void* const* d_in, const int* in_sizes, int n_in,
                              void* d_out, int out_size, void* d_ws, size_t ws_size,
                              hipStream_t stream) {
  const float* flags = (const float*)d_in[0];
  const float* W     = (const float*)d_in[1];
  float* out         = (float*)d_out;

  hipLaunchKernelGGL(prep_b_kernel, dim3(16), dim3(256), 0, stream, W);
  hipLaunchKernelGGL(flagbag_kernel, dim3(512), dim3(1024), 0, stream, flags, out);
}